// Round 1
// baseline (107.174 us; speedup 1.0000x reference)
//
#include <hip/hip_runtime.h>
#include <math.h>

#define KCOMP 8192
#define NSAMP 8192
#define BX 2048
#define DW 13

#define LOG2PI  1.8378770664093453f
#define LOGBETA 1.6094379124341003f   // ln(5)
#define LOGK    9.0109131020929380f   // ln(8192)
#define LOG2E   1.4426950408889634f
#define LN2     0.6931471805599453f
#define C2E     2.8853900817779268f   // 2*log2(e)

#define NBLK_KL   1024                // 128 rowtiles x 8 comp-chunks (R11-proven)
#define NBLK_DATA 512                 // 4 waves x 4 rows = 16 rows/block
#define NBLK_MONO (NBLK_KL + NBLK_DATA)

// knot grid: yp(x) piecewise-linear per row; data term is a quadratic form
// in the 513 knot values with x/y-only coefficients (P/L/C stats).
#define NK     512
#define XLO    (-4.75f)
#define DXK    (9.5f / (float)NK)
#define USCALE ((float)NK / 9.5f)

typedef __attribute__((ext_vector_type(8))) short bf16x8_t;
typedef __attribute__((ext_vector_type(4))) float f32x4_t;

__device__ __forceinline__ float fast_log(float x) {
    return __builtin_amdgcn_logf(x) * LN2;
}
__device__ __forceinline__ float softplus_stable(float x) {
    return fmaxf(x, 0.0f) + log1pf(expf(-fabsf(x)));
}
__device__ __forceinline__ unsigned short to_bf16(float f) {
    unsigned int u = __builtin_bit_cast(unsigned int, f);
    u += 0x7FFFu + ((u >> 16) & 1u);
    return (unsigned short)(u >> 16);
}
__device__ __forceinline__ float from_bf16(unsigned short h) {
    unsigned int u = ((unsigned int)h) << 16;
    return __builtin_bit_cast(float, u);
}
// tanh pair from pre-scaled args a_i = 2*log2e*z_i, one shared rcp:
// 3 trans + 7 VALU per pair. Overflow d0*d1=inf -> t=1 (correct branch).
// Verified end-to-end R9-R12 (absmax 0.0).
__device__ __forceinline__ void tanh_pair(float a0, float a1, float& t0, float& t1) {
    float e0 = __builtin_amdgcn_exp2f(a0);
    float e1 = __builtin_amdgcn_exp2f(a1);
    float d0 = e0 + 1.0f, d1 = e1 + 1.0f;
    float inv = __builtin_amdgcn_rcpf(d0 * d1);
    t0 = fmaf(-2.0f, d1 * inv, 1.0f);
    t1 = fmaf(-2.0f, d0 * inv, 1.0f);
}

// ---- ws float offsets ----
#define OFF_PART  0        // float[512]   data-role partials
#define OFF_RSUM  2048     // float[8192]  zeroed by prep
#define OFF_G2    10240    // float[8192]  f2*LOG2E
#define OFF_A2    18432    // float[8192]  f1*LOG2E
#define OFF_HQ    26624    // float[8192]  0.5||w||^2
#define OFF_PL    34816    // float[8192]  pivot*LOG2E
#define OFF_WF    43008    // float[8192*16]  f32 w, padded
#define OFF_WB    174080   // ushort[8192*32] hi/lo bf16 split of w
#define OFF_EMPB  305152   // ushort[8192*32] bf16(e) duplicated
#define OFF_STATP 436224   // float[576]  quad coeff per knot (zero-padded past 512)
#define OFF_STATL 436800   // float[576]  linear coeff per knot
#define OFF_STATC 437376   // float[576]  cross coeff per knot
#define OFF_SYY   437952   // float       sum y^2

// ================================================ prep: 64 work blocks + 1 stats block
__global__ __launch_bounds__(256) void prep_kernel(
        const float* __restrict__ emp, const float* __restrict__ rhos,
        const float* __restrict__ eps, const int* __restrict__ idxs,
        const float* __restrict__ x, const float* __restrict__ y,
        float* __restrict__ ws) {
    __shared__ float sb[5 * NK];   // S11 | Sff | S1f | S1y | Sfy
    __shared__ float sred[4];
    int tid = threadIdx.x;

    if (blockIdx.x < 64) {
        int g = blockIdx.x * 256 + tid;      // 0..16383
        if (g < KCOMP) {
            int j = g;
            ws[OFF_RSUM + j] = 0.0f;
            unsigned short* empB = (unsigned short*)(ws + OFF_EMPB);
            float sp  = softplus_stable(rhos[j]);
            float var = sp * sp;
            float inv = 1.0f / var;
            float esq = 0.0f;
            #pragma unroll
            for (int c = 0; c < DW; ++c) {
                float e = emp[j * DW + c];
                esq = fmaf(e, e, esq);
                unsigned short eb = to_bf16(e);
                empB[j * 32 + c]      = eb;
                empB[j * 32 + 16 + c] = eb;
            }
            #pragma unroll
            for (int c = DW; c < 16; ++c) { empB[j*32+c] = 0; empB[j*32+16+c] = 0; }
            float f1v = -6.5f * (LOG2PI + logf(var)) - 0.5f * esq * inv;
            ws[OFF_G2 + j] = inv * LOG2E;
            ws[OFF_A2 + j] = f1v * LOG2E;
        } else {
            int b  = g - KCOMP;
            int i0 = idxs[b];
            unsigned short* wB = (unsigned short*)(ws + OFF_WB);
            float* wF = ws + OFF_WF;
            float sp  = softplus_stable(rhos[i0]);
            float var = sp * sp;
            float inv = 1.0f / var;
            float esq = 0.0f, wsq = 0.0f, dot = 0.0f;
            #pragma unroll
            for (int c = 0; c < DW; ++c) {
                float e  = emp[i0 * DW + c];
                float wc = fmaf(eps[b * DW + c], sp, e);
                esq = fmaf(e, e, esq);
                wsq = fmaf(wc, wc, wsq);
                dot = fmaf(wc, e, dot);
                wF[b * 16 + c] = wc;
                unsigned short hi = to_bf16(wc);
                wB[b * 32 + c]      = hi;
                wB[b * 32 + 16 + c] = to_bf16(wc - from_bf16(hi));
            }
            #pragma unroll
            for (int c = DW; c < 16; ++c) { wF[b*16+c] = 0.0f; wB[b*32+c] = 0; wB[b*32+16+c] = 0; }
            float f1v = -6.5f * (LOG2PI + logf(var)) - 0.5f * esq * inv;
            float h   = 0.5f * wsq;
            ws[OFF_HQ + b] = h;
            ws[OFF_PL + b] = fmaf(inv, dot - h, f1v) * LOG2E;
        }
        return;
    }

    // ---------------- stats block: bin moments of (x, y) ----------------
    float* sS11 = sb;
    float* sSff = sb + NK;
    float* sS1f = sb + 2 * NK;
    float* sS1y = sb + 3 * NK;
    float* sSfy = sb + 4 * NK;
    for (int i = tid; i < 5 * NK; i += 256) sb[i] = 0.0f;
    __syncthreads();

    float syy = 0.0f;
    for (int p = tid; p < BX; p += 256) {
        float xv = x[p], yv = y[p];
        float u = fmaf(xv, USCALE, (float)(NK / 2));
        u = fminf(fmaxf(u, 0.0f), (float)NK - 0.001f);   // same binning as proven lerp
        int   i = (int)u;
        float f = u - (float)i;
        float g1 = 1.0f - f;
        atomicAdd(&sS11[i], g1 * g1);
        atomicAdd(&sSff[i], f * f);
        atomicAdd(&sS1f[i], g1 * f);
        atomicAdd(&sS1y[i], g1 * yv);
        atomicAdd(&sSfy[i], f * yv);
        syy = fmaf(yv, yv, syy);
    }
    __syncthreads();

    // per-knot coefficients: Q_r = sum_j a_j*(a_j*P_j + L_j + a_{j+1}*C_j) + Syy
    for (int j = tid; j < 576; j += 256) {
        float pj = 0.0f, lj = 0.0f, cj = 0.0f;
        if (j < NK)            { pj  = sS11[j];     lj  = sS1y[j];     cj = 2.0f * sS1f[j]; }
        if (j >= 1 && j <= NK) { pj += sSff[j - 1]; lj += sSfy[j - 1]; }
        ws[OFF_STATP + j] = pj;
        ws[OFF_STATL + j] = -2.0f * lj;
        ws[OFF_STATC + j] = cj;
    }

    int wv = tid >> 6, ln = tid & 63;
    #pragma unroll
    for (int o = 32; o; o >>= 1) syy += __shfl_down(syy, o);
    if (ln == 0) sred[wv] = syy;
    __syncthreads();
    if (tid == 0) ws[OFF_SYY] = sred[0] + sred[1] + sred[2] + sred[3];
}

// ================================================ main: kl (0..1023) + data (1024..1535)
__global__ __launch_bounds__(256) void main_kernel(float* __restrict__ ws) {
    __shared__ float red[4];
    int tid = threadIdx.x, wave = tid >> 6, lane = tid & 63;

    float* part = ws + OFF_PART;
    float* rsum = ws + OFF_RSUM;
    const float* G2  = ws + OFF_G2;
    const float* A2  = ws + OFF_A2;
    const float* hqA = ws + OFF_HQ;
    const float* plA = ws + OFF_PL;
    const float* wF  = ws + OFF_WF;
    const unsigned short* wB   = (const unsigned short*)(ws + OFF_WB);
    const unsigned short* empB = (const unsigned short*)(ws + OFF_EMPB);

    if (blockIdx.x >= NBLK_KL) {
        // ---------------- data role: quadratic form over knot values ----------------
        int d = blockIdx.x - NBLK_KL;        // 0..511
        const float* statP = ws + OFF_STATP;
        const float* statL = ws + OFF_STATL;
        const float* statC = ws + OFF_STATC;

        float P[9], L[9], C[9];
        #pragma unroll
        for (int t = 0; t < 9; ++t) {
            int j = t * 64 + lane;           // padded to 576: j>512 reads zeros
            P[t] = statP[j];
            L[t] = statL[j];
            C[t] = statC[j];
        }

        float q = 0.0f;
        int row0 = (d * 4 + wave) * 4;       // 4 rows per wave
        #pragma unroll 1
        for (int rr = 0; rr < 4; ++rr) {
            int row = row0 + rr;
            const float4* wr = (const float4*)(wF + row * 16);
            float4 wa = wr[0], wbv = wr[1], wcv = wr[2], wdv = wr[3];
            float s0 = wa.x * C2E, s1 = wa.y * C2E, s2 = wa.z * C2E, s3 = wa.w * C2E;
            float s4 = wbv.x * C2E, s5 = wbv.y * C2E, s6 = wbv.z * C2E, s7 = wbv.w * C2E;
            float s8 = wcv.x * C2E, s9 = wcv.y * C2E;
            float w10 = wcv.z, w11 = wcv.w, w12 = wdv.x;

            float k[10];
            #pragma unroll
            for (int t = 0; t < 9; ++t) {
                float xk = fmaf((float)(t * 64 + lane), DXK, XLO);
                float h10, h11, h20, h21;
                tanh_pair(fmaf(s0, xk, s2), fmaf(s1, xk, s3), h10, h11);
                tanh_pair(fmaf(s4, h10, fmaf(s5, h11, s8)),
                          fmaf(s6, h10, fmaf(s7, h11, s9)), h20, h21);
                k[t] = fmaf(w10, h20, fmaf(w11, h21, w12));
            }
            k[9] = k[0];                      // t=8 wrap: C=0 there, value unused

            #pragma unroll
            for (int t = 0; t < 9; ++t) {
                float a   = k[t];
                float an  = __shfl(k[t], (lane + 1) & 63);
                float an0 = __shfl(k[t + 1], 0);
                an = (lane == 63) ? an0 : an;
                float tq = fmaf(a, P[t], L[t]);
                tq = fmaf(an, C[t], tq);
                q = fmaf(a, tq, q);
            }
        }
        #pragma unroll
        for (int o = 32; o; o >>= 1) q += __shfl_down(q, o);
        if (lane == 0) red[wave] = q;
        __syncthreads();
        if (tid == 0) part[d] = red[0] + red[1] + red[2] + red[3];
    } else {
        // ---------------- kl role: MFMA GEMM + fused exp epilogue (unchanged) ----------------
        int bid     = blockIdx.x;              // 0..1023
        int rowtile = bid & 127;
        int chunk   = bid >> 7;                // 0..7
        int rowbase = rowtile * 64 + wave * 16;
        int half = lane >> 4;
        int m16  = lane & 15;

        const bf16x8_t afrag = *(const bf16x8_t*)(wB + (rowbase + m16) * 32 + half * 8);
        float h[4], p[4];
        #pragma unroll
        for (int r = 0; r < 4; ++r) {
            h[r] = hqA[rowbase + half * 4 + r];
            p[r] = plA[rowbase + half * 4 + r];
        }
        float s[4] = {0.f, 0.f, 0.f, 0.f};

        int j0 = chunk * (KCOMP / 8);
        #pragma unroll 2
        for (int jt = 0; jt < (KCOMP / 8) / 16; ++jt) {
            int j = j0 + jt * 16 + m16;
            bf16x8_t bfrag = *(const bf16x8_t*)(empB + j * 32 + half * 8);
            f32x4_t c = {0.f, 0.f, 0.f, 0.f};
            c = __builtin_amdgcn_mfma_f32_16x16x32_bf16(afrag, bfrag, c, 0, 0, 0);
            float g2 = G2[j], a2 = A2[j];
            #pragma unroll
            for (int r = 0; r < 4; ++r) {
                float t = fmaf(-g2, h[r], a2 - p[r]);
                s[r] += __builtin_amdgcn_exp2f(fmaf(g2, c[r], t));
            }
        }
        #pragma unroll
        for (int r = 0; r < 4; ++r) {
            float S = s[r];
            S += __shfl_xor(S, 1); S += __shfl_xor(S, 2);
            S += __shfl_xor(S, 4); S += __shfl_xor(S, 8);
            if (m16 == 0) atomicAdd(&rsum[rowbase + half * 4 + r], S);
        }
    }
}

// ================================================ finalize (1024 threads)
__global__ __launch_bounds__(1024) void fin_kernel(
        const float* __restrict__ ws, float* __restrict__ out) {
    __shared__ float red1[16], red2[16];
    int tid = threadIdx.x, wave = tid >> 6, lane = tid & 63;

    const float* part = ws + OFF_PART;
    const float* rsum = ws + OFF_RSUM;
    const float* hqA  = ws + OFF_HQ;
    const float* plA  = ws + OFF_PL;

    float s1 = 0.0f;
    for (int i = tid; i < NBLK_DATA; i += 1024) s1 += part[i];
    float s2 = 0.0f;
    for (int b = tid; b < NSAMP; b += 1024) {
        float q     = plA[b] * LN2 + fast_log(rsum[b]) - LOGK;
        float prior = -hqA[b] - 6.5f * LOG2PI;
        s2 += q - prior;
    }
    #pragma unroll
    for (int o = 32; o; o >>= 1) { s1 += __shfl_down(s1, o); s2 += __shfl_down(s2, o); }
    if (lane == 0) { red1[wave] = s1; red2[wave] = s2; }
    __syncthreads();
    if (tid < 16) {
        s1 = red1[tid]; s2 = red2[tid];
        #pragma unroll
        for (int o = 8; o; o >>= 1) { s1 += __shfl_down(s1, o); s2 += __shfl_down(s2, o); }
        if (tid == 0) {
            float syy = ws[OFF_SYY];
            // sum_r Q_r = sum(part) + NSAMP*syy
            float data_lp = -2.5f * (s1 / (float)NSAMP + syy)
                            + (float)BX * 0.5f * (LOGBETA - LOG2PI);
            out[0] = data_lp - s2 / (float)NSAMP;
        }
    }
}

extern "C" void kernel_launch(void* const* d_in, const int* in_sizes, int n_in,
                              void* d_out, int out_size, void* d_ws, size_t ws_size,
                              hipStream_t stream) {
    const float* emp  = (const float*)d_in[0];
    const float* rhos = (const float*)d_in[1];
    const float* x    = (const float*)d_in[2];
    const float* y    = (const float*)d_in[3];
    const float* eps  = (const float*)d_in[4];
    const int*   idxs = (const int*)d_in[5];
    float* out = (float*)d_out;
    float* ws  = (float*)d_ws;

    prep_kernel<<<65, 256, 0, stream>>>(emp, rhos, eps, idxs, x, y, ws);
    main_kernel<<<NBLK_MONO, 256, 0, stream>>>(ws);
    fin_kernel<<<1, 1024, 0, stream>>>(ws, out);
}